// Round 2
// baseline (648.450 us; speedup 1.0000x reference)
//
#include <hip/hip_runtime.h>
#include <math.h>

// B=64, N_total=1029, D=768, r=64, E=4, TOPK=1. Tokens = 65856 (= 1029*64).
// Routing (logits/softmax/argmax) must be f32-exact vs numpy: bf16 noise in t
// or logits flips near-tie argmax -> ~0.5-1.5 absmax error. So GEMM1 + logits
// stay f32; expert matmul + up-proj (value paths) use bf16 MFMA.

#define GELU(v) (0.5f*(v)*(1.0f + erff((v)*0.70710678118654752440f)))

typedef __attribute__((ext_vector_type(8))) short short8;
typedef __attribute__((ext_vector_type(4))) float f32x4;

__device__ __forceinline__ short f2bf(float f) {
    union { float f; unsigned u; } c; c.f = f;
    unsigned u = c.u;
    return (short)((u + 0x7fffu + ((u >> 16) & 1u)) >> 16);   // RTNE
}

// ---------------------------------------------------------------------------
// Prep: convert We (16384) and Wu (49152) f32 -> bf16 into workspace.
// ---------------------------------------------------------------------------
__global__ void k0_prep(const float* __restrict__ We, const float* __restrict__ Wu,
                        short* __restrict__ WeB, short* __restrict__ WuB) {
    int i = blockIdx.x * 256 + threadIdx.x;
    if (i < 16384)       WeB[i] = f2bf(We[i]);
    else if (i < 65536)  WuB[i - 16384] = f2bf(Wu[i - 16384]);
}

// ---------------------------------------------------------------------------
// Kernel 1 (f32, exact-ish): h = gelu(x . Wd^T). M=65856, N=64, K=768.
// K-tile 32 (17.9KB LDS -> ~6 blocks/CU) + register prefetch double-buffer.
// ---------------------------------------------------------------------------
__global__ __launch_bounds__(256, 6) void k1_proj_gelu(
    const float* __restrict__ x, const float* __restrict__ Wd,
    float* __restrict__ h)
{
    __shared__ float As[64][36];
    __shared__ float Bs[32][68];
    const int tid = threadIdx.x;
    const int bm  = blockIdx.x;
    const int tm4 = (tid >> 4) << 2;
    const int tn4 = (tid & 15) << 2;
    const float* xblk = x + (size_t)bm * 64 * 768;

    float acc[4][4];
    #pragma unroll
    for (int i = 0; i < 4; ++i)
        #pragma unroll
        for (int j = 0; j < 4; ++j) acc[i][j] = 0.f;

    // stage tile 0
    #pragma unroll
    for (int p = 0; p < 2; ++p) {
        int li = p*1024 + tid*4;
        int m = li >> 5, k = li & 31;
        *(f32x4*)&As[m][k] = *(const f32x4*)(xblk + m*768 + k);
        int j = m;
        f32x4 v = *(const f32x4*)(Wd + j*768 + k);
        int c = j ^ (((k >> 2) & 7) << 2);
        Bs[k+0][c] = v.x; Bs[k+1][c] = v.y; Bs[k+2][c] = v.z; Bs[k+3][c] = v.w;
    }
    __syncthreads();

    for (int kt = 0; kt < 768; kt += 32) {
        const bool more = (kt + 32) < 768;
        f32x4 nxa[2], nxb[2];
        if (more) {
            #pragma unroll
            for (int p = 0; p < 2; ++p) {
                int li = p*1024 + tid*4;
                int m = li >> 5, k = li & 31;
                nxa[p] = *(const f32x4*)(xblk + m*768 + kt + 32 + k);
                nxb[p] = *(const f32x4*)(Wd  + m*768 + kt + 32 + k);
            }
        }
        #pragma unroll
        for (int kk = 0; kk < 32; kk += 4) {
            const int swz = ((kk >> 2) & 7) << 2;
            f32x4 av[4], bv[4];
            #pragma unroll
            for (int i = 0; i < 4; ++i) av[i] = *(const f32x4*)&As[tm4 + i][kk];
            #pragma unroll
            for (int r = 0; r < 4; ++r) bv[r] = *(const f32x4*)&Bs[kk + r][tn4 ^ swz];
            #pragma unroll
            for (int i = 0; i < 4; ++i) {
                acc[i][0] += av[i].x*bv[0].x; acc[i][1] += av[i].x*bv[0].y;
                acc[i][2] += av[i].x*bv[0].z; acc[i][3] += av[i].x*bv[0].w;
                acc[i][0] += av[i].y*bv[1].x; acc[i][1] += av[i].y*bv[1].y;
                acc[i][2] += av[i].y*bv[1].z; acc[i][3] += av[i].y*bv[1].w;
                acc[i][0] += av[i].z*bv[2].x; acc[i][1] += av[i].z*bv[2].y;
                acc[i][2] += av[i].z*bv[2].z; acc[i][3] += av[i].z*bv[2].w;
                acc[i][0] += av[i].w*bv[3].x; acc[i][1] += av[i].w*bv[3].y;
                acc[i][2] += av[i].w*bv[3].z; acc[i][3] += av[i].w*bv[3].w;
            }
        }
        __syncthreads();
        if (more) {
            #pragma unroll
            for (int p = 0; p < 2; ++p) {
                int li = p*1024 + tid*4;
                int m = li >> 5, k = li & 31;
                *(f32x4*)&As[m][k] = nxa[p];
                int c = m ^ (((k >> 2) & 7) << 2);
                Bs[k+0][c] = nxb[p].x; Bs[k+1][c] = nxb[p].y;
                Bs[k+2][c] = nxb[p].z; Bs[k+3][c] = nxb[p].w;
            }
            __syncthreads();
        }
    }
    #pragma unroll
    for (int i = 0; i < 4; ++i) {
        int token = bm*64 + tm4 + i;
        f32x4 o;
        o.x = GELU(acc[i][0]); o.y = GELU(acc[i][1]);
        o.z = GELU(acc[i][2]); o.w = GELU(acc[i][3]);
        *(f32x4*)(h + (size_t)token*64 + tn4) = o;
    }
}

// ---------------------------------------------------------------------------
// Kernel 23 (fused MoE + up-proj): per 64-token tile:
//  - stage h (f32) in LDS
//  - f32 logits/softmax/top-1 (w=0 for cls/rel positions)
//  - expert_all for ALL 4 experts via bf16 MFMA, in-register select+combine
//  - full written back to LDS, GEMM2 (full . Wu^T)*gamma via bf16 MFMA
// MFMA 16x16x32 bf16: A[m=lane&15][k=(lane>>4)*8+j]; B[k][n=lane&15];
// C: col=lane&15, row=(lane>>4)*4+reg (m89-verified).
// ---------------------------------------------------------------------------
__global__ __launch_bounds__(256, 4) void k23_moe_up(
    const float* __restrict__ h, const short* __restrict__ WeB,
    const short* __restrict__ WuB, const float* __restrict__ Wg,
    const float* __restrict__ be, const float* __restrict__ gamma,
    float* __restrict__ out)
{
    __shared__ float hS[64][68];
    __shared__ float sWg[4][68];
    __shared__ float sBe[4][68];
    __shared__ float sGm[768];
    __shared__ float sLg[64][5];
    __shared__ float sW[64];
    __shared__ int   sEi[64];

    const int tid = threadIdx.x;
    const int tb  = blockIdx.x * 64;

    #pragma unroll
    for (int p = 0; p < 4; ++p) {
        int li = p*1024 + tid*4;
        int m = li >> 6, k = li & 63;
        *(f32x4*)&hS[m][k] = *(const f32x4*)(h + (size_t)(tb + m)*64 + k);
    }
    { int e = tid >> 6, k = tid & 63;
      sWg[e][k] = Wg[tid]; sBe[e][k] = be[tid]; }
    for (int i = tid; i < 768; i += 256) sGm[i] = gamma[i];
    __syncthreads();

    // f32 logits: thread = (token, expert)
    {
        int tok = tid >> 2, e = tid & 3;
        float s = 0.f;
        #pragma unroll 8
        for (int k = 0; k < 64; ++k) s += hS[tok][k] * sWg[e][k];
        sLg[tok][e] = s;
    }
    __syncthreads();
    if (tid < 64) {
        float l0 = sLg[tid][0], l1 = sLg[tid][1], l2 = sLg[tid][2], l3 = sLg[tid][3];
        int ei = 0; float lm = l0;
        if (l1 > lm) { lm = l1; ei = 1; }
        if (l2 > lm) { lm = l2; ei = 2; }
        if (l3 > lm) { lm = l3; ei = 3; }
        float s = expf(l0-lm) + expf(l1-lm) + expf(l2-lm) + expf(l3-lm);
        unsigned token = tb + tid;
        unsigned pos = token % 1029u;
        sW[tid]  = (pos < 5u) ? 0.f : (1.f / s);
        sEi[tid] = ei;
    }
    __syncthreads();

    const int wv = tid >> 6, lane = tid & 63;
    const int q = lane >> 4, c = lane & 15;
    const int r0 = wv * 16;

    // A-frags (t, bf16) for this wave's 16 rows
    short8 af[2];
    #pragma unroll
    for (int ks = 0; ks < 2; ++ks) {
        const float* p = &hS[r0 + c][ks*32 + q*8];
        f32x4 v0 = *(const f32x4*)p, v1 = *(const f32x4*)(p + 4);
        short8 a;
        a[0]=f2bf(v0.x); a[1]=f2bf(v0.y); a[2]=f2bf(v0.z); a[3]=f2bf(v0.w);
        a[4]=f2bf(v1.x); a[5]=f2bf(v1.y); a[6]=f2bf(v1.z); a[7]=f2bf(v1.w);
        af[ks] = a;
    }

    // expert_all for all 4 experts: eacc[e][st]
    f32x4 eacc[4][4];
    #pragma unroll
    for (int e = 0; e < 4; ++e)
        #pragma unroll
        for (int st = 0; st < 4; ++st) {
            f32x4 acc = {0.f, 0.f, 0.f, 0.f};
            #pragma unroll
            for (int ks = 0; ks < 2; ++ks) {
                short8 b = *(const short8*)(WeB + ((e*64 + st*16 + c)*64 + ks*32 + q*8));
                acc = __builtin_amdgcn_mfma_f32_16x16x32_bf16(af[ks], b, acc, 0, 0, 0);
            }
            eacc[e][st] = acc;
        }

    // combine: full = t + w*(expert_all[ei] + be[ei]); overwrite hS with full
    float wq[4]; int eq[4];
    #pragma unroll
    for (int reg = 0; reg < 4; ++reg) {
        int row = r0 + q*4 + reg;
        wq[reg] = sW[row]; eq[reg] = sEi[row];
    }
    float tv[4][4];
    #pragma unroll
    for (int st = 0; st < 4; ++st)
        #pragma unroll
        for (int reg = 0; reg < 4; ++reg)
            tv[st][reg] = hS[r0 + q*4 + reg][st*16 + c];
    #pragma unroll
    for (int st = 0; st < 4; ++st)
        #pragma unroll
        for (int reg = 0; reg < 4; ++reg) {
            int ei = eq[reg];
            float ea = (ei == 0) ? eacc[0][st][reg] :
                       (ei == 1) ? eacc[1][st][reg] :
                       (ei == 2) ? eacc[2][st][reg] : eacc[3][st][reg];
            float bev = sBe[ei][st*16 + c];
            hS[r0 + q*4 + reg][st*16 + c] = tv[st][reg] + wq[reg]*(ea + bev);
        }
    __syncthreads();

    // GEMM2: out = (full . Wu^T) * gamma
    short8 af2[2];
    #pragma unroll
    for (int ks = 0; ks < 2; ++ks) {
        const float* p = &hS[r0 + c][ks*32 + q*8];
        f32x4 v0 = *(const f32x4*)p, v1 = *(const f32x4*)(p + 4);
        short8 a;
        a[0]=f2bf(v0.x); a[1]=f2bf(v0.y); a[2]=f2bf(v0.z); a[3]=f2bf(v0.w);
        a[4]=f2bf(v1.x); a[5]=f2bf(v1.y); a[6]=f2bf(v1.z); a[7]=f2bf(v1.w);
        af2[ks] = a;
    }
    #pragma unroll 4
    for (int nt = 0; nt < 48; ++nt) {
        f32x4 acc = {0.f, 0.f, 0.f, 0.f};
        short8 b0 = *(const short8*)(WuB + ((nt*16 + c)*64 + q*8));
        short8 b1 = *(const short8*)(WuB + ((nt*16 + c)*64 + 32 + q*8));
        acc = __builtin_amdgcn_mfma_f32_16x16x32_bf16(af2[0], b0, acc, 0, 0, 0);
        acc = __builtin_amdgcn_mfma_f32_16x16x32_bf16(af2[1], b1, acc, 0, 0, 0);
        float g = sGm[nt*16 + c];
        #pragma unroll
        for (int reg = 0; reg < 4; ++reg)
            out[(size_t)(tb + r0 + q*4 + reg)*768 + nt*16 + c] = acc[reg] * g;
    }
}

extern "C" void kernel_launch(void* const* d_in, const int* in_sizes, int n_in,
                              void* d_out, int out_size, void* d_ws, size_t ws_size,
                              hipStream_t stream) {
    const float* x     = (const float*)d_in[0];
    const float* Wd    = (const float*)d_in[1];
    const float* Wg    = (const float*)d_in[2];
    const float* We    = (const float*)d_in[3];
    const float* be    = (const float*)d_in[4];
    const float* Wu    = (const float*)d_in[5];
    const float* gamma = (const float*)d_in[6];
    float* out = (float*)d_out;

    short* WeB = (short*)d_ws;                       // 16384 bf16 = 32 KB
    short* WuB = (short*)d_ws + 16384;               // 49152 bf16 = 96 KB
    float* h   = (float*)((char*)d_ws + 131072);     // 65856*64 f32 = 16.9 MB

    k0_prep<<<256, 256, 0, stream>>>(We, Wu, WeB, WuB);
    k1_proj_gelu<<<1029, 256, 0, stream>>>(x, Wd, h);
    k23_moe_up<<<1029, 256, 0, stream>>>(h, WeB, WuB, Wg, be, gamma, out);
}